// Round 1
// baseline (238.838 us; speedup 1.0000x reference)
//
#include <hip/hip_runtime.h>
#include <hip/hip_bf16.h>
#include <math.h>

// z_t = a*x_t + b*z_{t-1}, z_{-1} = 0, per row. a = 0.5*tanh(raw_a), b = tanh(raw_b).
// One wave (64 lanes) per row; 8 elems/lane/chunk -> 512-elem chunks; 16 chunks over T=8192.
// Cross-lane affine scan uses precomputed per-lane powers of b^8 (b^8 >= 0, so powf is safe
// even for negative b; signed powers b^1..b^8 built by direct multiplication).

#define T_LEN  8192
#define EPT    8
#define CHUNK  (64 * EPT)          // 512
#define NCHUNK (T_LEN / CHUNK)     // 16

__global__ __launch_bounds__(256) void lincell_scan(
    const float* __restrict__ X,
    const float* __restrict__ pa,
    const float* __restrict__ pb,
    float* __restrict__ Z,
    int nrows)
{
    const int gtid = blockIdx.x * blockDim.x + threadIdx.x;
    const int row  = gtid >> 6;
    const int lane = threadIdx.x & 63;
    if (row >= nrows) return;

    const float a = 0.5f * tanhf(pa[0]);
    const float b = tanhf(pb[0]);

    // signed powers b^1..b^8 (exact sign handling via multiplication)
    const float b2 = b  * b;
    const float b3 = b2 * b;
    const float b4 = b2 * b2;
    const float b5 = b4 * b;
    const float b6 = b4 * b2;
    const float b7 = b4 * b3;
    const float b8 = b4 * b4;      // >= 0 always

    // Cross-lane scan multipliers: before step k (offset d = 2^k), this lane's
    // accumulated affine multiplier is b8^min(lane+1, d).
    float mstep[6];
#pragma unroll
    for (int k = 0; k < 6; ++k) {
        const int d = 1 << k;
        const int e = (lane + 1 < d) ? (lane + 1) : d;
        mstep[k] = powf(b8, (float)e);
    }
    const float b8lane = powf(b8, (float)lane);   // b^(8*lane), base >= 0
    const float cdecay = powf(b8, 64.0f);         // b^512 chunk-to-chunk decay

    const float* xrow = X + (size_t)row * T_LEN;
    float*       zrow = Z + (size_t)row * T_LEN;

    float carry = 0.0f;   // z state entering current chunk

#pragma unroll 2
    for (int c = 0; c < NCHUNK; ++c) {
        const float4* px = reinterpret_cast<const float4*>(xrow + (size_t)c * CHUNK) + (lane * 2);
        const float4 v0 = px[0];
        const float4 v1 = px[1];

        // in-lane serial scan (zero-init local contribution)
        const float y0 = a * v0.x;
        const float y1 = fmaf(b, y0, a * v0.y);
        const float y2 = fmaf(b, y1, a * v0.z);
        const float y3 = fmaf(b, y2, a * v0.w);
        const float y4 = fmaf(b, y3, a * v1.x);
        const float y5 = fmaf(b, y4, a * v1.y);
        const float y6 = fmaf(b, y5, a * v1.z);
        const float y7 = fmaf(b, y6, a * v1.w);

        // cross-lane inclusive scan of lane totals (affine with constant decay)
        float s = y7;
#pragma unroll
        for (int k = 0; k < 6; ++k) {
            float t = __shfl_up(s, (unsigned)(1 << k), 64);
            t = (lane >= (1 << k)) ? t : 0.0f;
            s = fmaf(mstep[k], t, s);
        }

        // exclusive prefix within chunk, then fold in the inter-chunk carry
        float excl = __shfl_up(s, 1u, 64);
        excl = (lane >= 1) ? excl : 0.0f;
        const float pre = fmaf(b8lane, carry, excl);  // z state before this lane's elems

        float4 o0, o1;
        o0.x = fmaf(b,  pre, y0);
        o0.y = fmaf(b2, pre, y1);
        o0.z = fmaf(b3, pre, y2);
        o0.w = fmaf(b4, pre, y3);
        o1.x = fmaf(b5, pre, y4);
        o1.y = fmaf(b6, pre, y5);
        o1.z = fmaf(b7, pre, y6);
        o1.w = fmaf(b8, pre, y7);

        float4* pz = reinterpret_cast<float4*>(zrow + (size_t)c * CHUNK) + (lane * 2);
        pz[0] = o0;
        pz[1] = o1;

        // carry across chunks: z_end = incl_(lane 63) + b^512 * carry
        const float last = __shfl(s, 63, 64);
        carry = fmaf(cdecay, carry, last);
    }
}

extern "C" void kernel_launch(void* const* d_in, const int* in_sizes, int n_in,
                              void* d_out, int out_size, void* d_ws, size_t ws_size,
                              hipStream_t stream) {
    const float* X  = (const float*)d_in[0];
    const float* pa = (const float*)d_in[1];
    const float* pb = (const float*)d_in[2];
    float* Z = (float*)d_out;

    const int nrows = in_sizes[0] / T_LEN;         // 4096
    const int waves_per_block = 4;                 // 256 threads
    const int blocks = (nrows + waves_per_block - 1) / waves_per_block;
    lincell_scan<<<blocks, 256, 0, stream>>>(X, pa, pb, Z, nrows);
}

// Round 2
// 236.044 us; speedup vs baseline: 1.0118x; 1.0118x over previous
//
#include <hip/hip_runtime.h>
#include <math.h>

// z_t = a*x_t + b*z_{t-1}, z_{-1}=0 per row; a = 0.5*tanh(raw_a), b = tanh(raw_b).
// One wave per row. Chunk = 1024 elems = 4 sub-blocks of 256; lane i owns 4
// contiguous elems per sub-block -> every dwordx4 load/store is unit-stride.
// Software-pipelined prefetch of the next chunk keeps 4KB/wave in flight.

typedef float f32x4 __attribute__((ext_vector_type(4)));

#define T_LEN  8192
#define NSUB   4
#define CHUNK  1024                 // NSUB * 64 lanes * 4 elems
#define NCHUNK (T_LEN / CHUNK)      // 8

__global__ __launch_bounds__(256) void lincell_scan(
    const float* __restrict__ X,
    const float* __restrict__ pa,
    const float* __restrict__ pb,
    float* __restrict__ Z,
    int nrows)
{
    const int gtid = blockIdx.x * blockDim.x + threadIdx.x;
    const int row  = gtid >> 6;
    const int lane = threadIdx.x & 63;
    if (row >= nrows) return;

    const float a  = 0.5f * tanhf(pa[0]);
    const float b  = tanhf(pb[0]);
    const float b2 = b * b;
    const float b3 = b2 * b;
    const float b4 = b2 * b2;            // >= 0 always

    // Cross-lane scan multipliers over lane totals (segment decay m = b^4):
    // before step k (offset d=2^k), this lane's accumulated multiplier is m^min(lane+1,d).
    float mstep[6];
#pragma unroll
    for (int k = 0; k < 6; ++k) {
        const int d = 1 << k;
        const int e = (lane + 1 < d) ? (lane + 1) : d;
        mstep[k] = powf(b4, (float)e);
    }
    const float b4lane = powf(b4, (float)lane);   // b^(4*lane), base >= 0
    const float bsub   = powf(b4, 64.0f);         // b^256 sub-block decay

    const f32x4* xrow = (const f32x4*)(X + (size_t)row * T_LEN);
    f32x4*       zrow = (f32x4*)(Z + (size_t)row * T_LEN);
    // chunk c, sub j: vector index c*256 + j*64 + lane  (unit-stride per instr)

    float carry = 0.0f;

    f32x4 cur[NSUB];
#pragma unroll
    for (int j = 0; j < NSUB; ++j) cur[j] = xrow[j * 64 + lane];

#pragma unroll
    for (int c = 0; c < NCHUNK; ++c) {
        // prefetch next chunk (issued before the dependent compute below)
        f32x4 nxt[NSUB];
        if (c + 1 < NCHUNK) {
#pragma unroll
            for (int j = 0; j < NSUB; ++j)
                nxt[j] = xrow[(c + 1) * 256 + j * 64 + lane];
        }

        // in-lane serial scans of 4 elems, 4 independent sub-blocks (ILP)
        float y0[NSUB], y1[NSUB], y2[NSUB], y3[NSUB], s[NSUB];
#pragma unroll
        for (int j = 0; j < NSUB; ++j) {
            y0[j] = a * cur[j].x;
            y1[j] = fmaf(b, y0[j], a * cur[j].y);
            y2[j] = fmaf(b, y1[j], a * cur[j].z);
            y3[j] = fmaf(b, y2[j], a * cur[j].w);
            s[j]  = y3[j];
        }

        // 4 independent cross-lane affine scans (constant decay -> fma only)
#pragma unroll
        for (int k = 0; k < 6; ++k) {
#pragma unroll
            for (int j = 0; j < NSUB; ++j) {
                float t = __shfl_up(s[j], (unsigned)(1 << k), 64);
                t = (lane >= (1 << k)) ? t : 0.0f;
                s[j] = fmaf(mstep[k], t, s[j]);
            }
        }

        float excl[NSUB], tot[NSUB];
#pragma unroll
        for (int j = 0; j < NSUB; ++j) {
            float e = __shfl_up(s[j], 1u, 64);
            excl[j] = (lane >= 1) ? e : 0.0f;
            tot[j]  = __shfl(s[j], 63, 64);
        }

        // serial sub-block chaining + outputs
        float cj = carry;
#pragma unroll
        for (int j = 0; j < NSUB; ++j) {
            const float pre = fmaf(b4lane, cj, excl[j]);  // z before lane's elems
            f32x4 o;
            o.x = fmaf(b,  pre, y0[j]);
            o.y = fmaf(b2, pre, y1[j]);
            o.z = fmaf(b3, pre, y2[j]);
            o.w = fmaf(b4, pre, y3[j]);
            __builtin_nontemporal_store(o, &zrow[c * 256 + j * 64 + lane]);
            cj = fmaf(bsub, cj, tot[j]);                  // carry into next sub
        }
        carry = cj;

#pragma unroll
        for (int j = 0; j < NSUB; ++j) cur[j] = nxt[j];
    }
}

extern "C" void kernel_launch(void* const* d_in, const int* in_sizes, int n_in,
                              void* d_out, int out_size, void* d_ws, size_t ws_size,
                              hipStream_t stream) {
    const float* X  = (const float*)d_in[0];
    const float* pa = (const float*)d_in[1];
    const float* pb = (const float*)d_in[2];
    float* Z = (float*)d_out;

    const int nrows = in_sizes[0] / T_LEN;   // 4096
    const int blocks = (nrows + 3) / 4;      // 4 waves (rows) per 256-thread block
    lincell_scan<<<blocks, 256, 0, stream>>>(X, pa, pb, Z, nrows);
}